// Round 17
// baseline (41.901 us; speedup 1.0000x reference)
//
#include <hip/hip_runtime.h>

// Problem constants
#define NT 64
#define NF 1024
#define NB 1024
#define ND 2048
#define NTP 32
#define NN2 (NT * NTP)
#define NP 27
#define NW2ROW 1027
#define BKK 128      // K-tile (per kt); each of 4 waves owns a K=32 slice
#define BM 64
#define BN 64

typedef __attribute__((ext_vector_type(8))) short short8;
typedef __attribute__((ext_vector_type(4))) float f32x4;

static __device__ __forceinline__ unsigned short f2bf(float x) {
    unsigned u = __float_as_uint(x);
    unsigned r = (u + 0x7FFFu + ((u >> 16) & 1u)) >> 16;   // RNE
    return (unsigned short)r;
}

// ---------------------------------------------------------------------------
// prep v5 (j-range split, unchanged from R16): grid 640 x 1024 threads.
// ---------------------------------------------------------------------------
__global__ __launch_bounds__(1024) void prep_kernel(
    const int* __restrict__ idx, const float* __restrict__ w_clc,
    const float* __restrict__ w1, const float* __restrict__ w2,
    const float* __restrict__ d, unsigned short* __restrict__ Wf,
    unsigned short* __restrict__ db)
{
    __shared__ __align__(16) float tile[21 * 256];   // 21,504 B
    int bid = blockIdx.x;
    int tid = threadIdx.x;

    if (bid < 512) {
        int t = bid >> 3, je = bid & 7;

        float4* tz = (float4*)tile;
        for (int i = tid; i < 1344; i += 1024) tz[i] = make_float4(0, 0, 0, 0);
        __syncthreads();

        {
            int f = tid;
            int j = idx[t * NF + f];
            if ((j >> 8) == je) {
                int jl = j & 255;
                float2 a = *(const float2*)&w_clc[(size_t)(t * NF + f) * 2];
                atomicAdd(&tile[0 * 256 + jl], a.x);
                atomicAdd(&tile[1 * 256 + jl], a.y);
                const float* p1 = &w1[(size_t)(t * NF + f) * 3];
                atomicAdd(&tile[2 * 256 + jl], p1[0]);
                atomicAdd(&tile[3 * 256 + jl], p1[1]);
                atomicAdd(&tile[4 * 256 + jl], p1[2]);
                const float* w2row = &w2[((size_t)t * NW2ROW + f) * 16];
                float4 q0 = *(const float4*)&w2row[0];
                float4 q1 = *(const float4*)&w2row[4];
                float4 q2 = *(const float4*)&w2row[8];
                float4 q3 = *(const float4*)&w2row[12];
                atomicAdd(&tile[ 5 * 256 + jl], q0.x);
                atomicAdd(&tile[ 6 * 256 + jl], q0.y);
                atomicAdd(&tile[ 7 * 256 + jl], q0.z);
                atomicAdd(&tile[ 8 * 256 + jl], q0.w);
                atomicAdd(&tile[ 9 * 256 + jl], q1.x);
                atomicAdd(&tile[10 * 256 + jl], q1.y);
                atomicAdd(&tile[11 * 256 + jl], q1.z);
                atomicAdd(&tile[12 * 256 + jl], q1.w);
                atomicAdd(&tile[13 * 256 + jl], q2.x);
                atomicAdd(&tile[14 * 256 + jl], q2.y);
                atomicAdd(&tile[15 * 256 + jl], q2.z);
                atomicAdd(&tile[16 * 256 + jl], q2.w);
                atomicAdd(&tile[17 * 256 + jl], q3.x);
                atomicAdd(&tile[18 * 256 + jl], q3.y);
                atomicAdd(&tile[19 * 256 + jl], q3.z);
                atomicAdd(&tile[20 * 256 + jl], q3.w);
            }
        }
        __syncthreads();

        for (int i = tid; i < 672; i += 1024) {
            int c = i >> 5, off = (i & 31) * 8;
            const float* tr = &tile[c * 256 + off];
            union { unsigned short u[8]; uint4 v; } pk;
#pragma unroll
            for (int e = 0; e < 8; ++e) pk.u[e] = f2bf(tr[e]);
            *(uint4*)&Wf[(size_t)(t * NTP + c) * ND + je * 256 + off] = pk.v;
        }
        uint4 z = make_uint4(0, 0, 0, 0);
        for (int i = tid; i < 352; i += 1024) {
            int c = 21 + (i >> 5), off = (i & 31) * 8;
            *(uint4*)&Wf[(size_t)(t * NTP + c) * ND + je * 256 + off] = z;
        }
    } else {
        int cb = bid - 512;
        int i16 = (cb * 1024 + tid) * 16;
#pragma unroll
        for (int h = 0; h < 2; ++h) {
            int i8 = i16 + h * 8;
            float4 a = *(const float4*)&d[i8];
            float4 b = *(const float4*)&d[i8 + 4];
            union { unsigned short u[8]; uint4 v; } pk;
            pk.u[0] = f2bf(a.x); pk.u[1] = f2bf(a.y); pk.u[2] = f2bf(a.z); pk.u[3] = f2bf(a.w);
            pk.u[4] = f2bf(b.x); pk.u[5] = f2bf(b.y); pk.u[6] = f2bf(b.z); pk.u[7] = f2bf(b.w);
            *(uint4*)&db[i8] = pk.v;
        }
    }
}

// ---------------------------------------------------------------------------
// Fused GEMM + epilogue, K-SPLIT-4 form. Grid (32, 16) = 512 blocks = 2/CU,
// block 256 = 4 waves. Tile 64x64 (2 trees), BK = 128, 16 kt.
// Wave w computes the FULL 64x64 tile for ITS K-quarter (offset w*32 of each
// BK): 4x4 fragments of 16x16x32 -> 8 ds_read_b128 per 16 MFMAs per kt
// (0.5 reads/MFMA, 2x the R16 ratio; the LDS pipe was the binding resource
// at MfmaUtil 18%). Counted-vmcnt pipeline kept (vmcnt(8): next tile's 8
// staging loads stay in flight across the barrier). XOR-swizzle on 16B slots
// (c ^ (row&15)) applied on the GLOBAL source (linear LDS dest, m104) and on
// the ds_read slot. After the K-loop: deterministic 4->1 cross-wave
// accumulator tree through LDS, then the unchanged per-(b,tree) epilogue.
// LDS 64KB/block -> 2 blocks/CU (128 <= 160KB).
// ---------------------------------------------------------------------------
__global__ __launch_bounds__(256, 2) void fused_kernel(
    const unsigned short* __restrict__ A,    // db [1024][2048]
    const unsigned short* __restrict__ Bm,   // Wf [2048][2048]
    const float* __restrict__ b_clc, const float* __restrict__ b1,
    const float* __restrict__ b2, const float* __restrict__ w2,
    const int* __restrict__ cc, float* __restrict__ ptl2)
{
    __shared__ __align__(16) char smem[65536];
    unsigned short (*As)[BM][BKK] = (unsigned short(*)[BM][BKK])smem;            // 2x16KB
    unsigned short (*Bs)[BN][BKK] = (unsigned short(*)[BN][BKK])(smem + 32768);  // 2x16KB
    // post-K-loop aliases (floats): s0/s1 partial slices, Cl, red
    float* s0  = (float*)smem;               // [64][66] = 16,896 B
    float* s1  = s0 + 64 * 66;               // [64][66]
    float* Cl  = s1 + 64 * 66;               // [64][66]
    float* red = Cl + 64 * 66;               // [27][64] = 6,912 B  (total 57,600)

    int tid = threadIdx.x;
    int lane = tid & 63;
    int wv = tid >> 6;          // 0..3 = K-slice owner
    int nb = blockIdx.x;        // n-tile (2 trees)
    int mb = blockIdx.y;        // m-tile (64 b)
    int m0 = mb * BM;
    int n0 = nb * BN;
    int r0 = lane & 15;
    int kq = lane >> 4;
    int slotbase = wv * 4 + kq;             // 16B-slot of this wave's K-slice

    f32x4 acc[4][4];
#pragma unroll
    for (int mi = 0; mi < 4; ++mi)
#pragma unroll
        for (int ni = 0; ni < 4; ++ni) acc[mi][ni] = (f32x4)0.f;

    // Staging: A and B each 1024 16B-chunks (64 rows x 16 slots), 4/thread;
    // linear LDS dest; global source slot pre-swizzled (c ^ (row&15)).
#define STAGE(buf, kt)                                                          \
    {                                                                           \
        size_t koff = (size_t)(kt) * BKK;                                       \
        _Pragma("unroll")                                                       \
        for (int p = 0; p < 4; ++p) {                                           \
            int chunk = p * 256 + tid;                                          \
            int row = chunk >> 4, c = chunk & 15;                               \
            int csw = (c ^ (row & 15)) * 8;                                     \
            const unsigned short* ga = A + (size_t)(m0 + row) * ND + koff + csw;\
            __builtin_amdgcn_global_load_lds(                                   \
                (const __attribute__((address_space(1))) void*)ga,              \
                (__attribute__((address_space(3))) void*)&As[buf][row][c * 8],  \
                16, 0, 0);                                                      \
        }                                                                       \
        _Pragma("unroll")                                                       \
        for (int p = 0; p < 4; ++p) {                                           \
            int chunk = p * 256 + tid;                                          \
            int row = chunk >> 4, c = chunk & 15;                               \
            int csw = (c ^ (row & 15)) * 8;                                     \
            const unsigned short* gb = Bm + (size_t)(n0 + row) * ND + koff + csw;\
            __builtin_amdgcn_global_load_lds(                                   \
                (const __attribute__((address_space(1))) void*)gb,              \
                (__attribute__((address_space(3))) void*)&Bs[buf][row][c * 8],  \
                16, 0, 0);                                                      \
        }                                                                       \
    }

    STAGE(0, 0);                 // 8 loads in flight

    int cur = 0;
    for (int kt = 0; kt < 16; ++kt) {
        if (kt < 15) {
            STAGE(cur ^ 1, kt + 1);                              // 16 in flight
            asm volatile("s_waitcnt vmcnt(8)" ::: "memory");     // tile kt done
        } else {
            asm volatile("s_waitcnt vmcnt(0)" ::: "memory");
        }
        __builtin_amdgcn_s_barrier();            // tile kt ready, all waves
        __builtin_amdgcn_sched_barrier(0);

        short8 af[4], bf[4];
#pragma unroll
        for (int mi = 0; mi < 4; ++mi)
            af[mi] = *(const short8*)&As[cur][mi * 16 + r0][(slotbase ^ r0) * 8];
#pragma unroll
        for (int ni = 0; ni < 4; ++ni)
            bf[ni] = *(const short8*)&Bs[cur][ni * 16 + r0][(slotbase ^ r0) * 8];
#pragma unroll
        for (int mi = 0; mi < 4; ++mi)
#pragma unroll
            for (int ni = 0; ni < 4; ++ni)
                acc[mi][ni] = __builtin_amdgcn_mfma_f32_16x16x32_bf16(
                    af[mi], bf[ni], acc[mi][ni], 0, 0, 0);

        __builtin_amdgcn_sched_barrier(0);
        __builtin_amdgcn_s_barrier();            // reads of buf cur done
        __builtin_amdgcn_sched_barrier(0);
        cur ^= 1;
    }
#undef STAGE

    // ---- deterministic 4->1 cross-wave K-partial reduction ----
    // acc element (mi,ni,q) sits at b-row = mi*16 + kq*4 + q, col = ni*16 + r0.
    // Stride 66 -> <=2-way banks.
    if (wv >= 2) {
        float* dst = (wv == 2) ? s0 : s1;
#pragma unroll
        for (int mi = 0; mi < 4; ++mi)
#pragma unroll
            for (int ni = 0; ni < 4; ++ni)
#pragma unroll
                for (int q = 0; q < 4; ++q)
                    dst[(mi * 16 + kq * 4 + q) * 66 + ni * 16 + r0] = acc[mi][ni][q];
    }
    __syncthreads();
    if (wv < 2) {
        const float* src = (wv == 0) ? s0 : s1;
#pragma unroll
        for (int mi = 0; mi < 4; ++mi)
#pragma unroll
            for (int ni = 0; ni < 4; ++ni)
#pragma unroll
                for (int q = 0; q < 4; ++q)
                    acc[mi][ni][q] += src[(mi * 16 + kq * 4 + q) * 66 + ni * 16 + r0];
    }
    __syncthreads();
    if (wv == 1) {
#pragma unroll
        for (int mi = 0; mi < 4; ++mi)
#pragma unroll
            for (int ni = 0; ni < 4; ++ni)
#pragma unroll
                for (int q = 0; q < 4; ++q)
                    s0[(mi * 16 + kq * 4 + q) * 66 + ni * 16 + r0] = acc[mi][ni][q];
    }
    __syncthreads();
    if (wv == 0) {
#pragma unroll
        for (int mi = 0; mi < 4; ++mi)
#pragma unroll
            for (int ni = 0; ni < 4; ++ni)
#pragma unroll
                for (int q = 0; q < 4; ++q) {
                    float v = acc[mi][ni][q] + s0[(mi * 16 + kq * 4 + q) * 66 + ni * 16 + r0];
                    Cl[(mi * 16 + kq * 4 + q) * 66 + ni * 16 + r0] = v;
                }
    }
    __syncthreads();

    // ---- epilogue: waves 0-1 = trees 0-1 (wave-uniform t), lane = b ----
    int tl = tid >> 6;
    int bl = lane;
    float s[NP];
#pragma unroll
    for (int k = 0; k < NP; ++k) s[k] = 0.f;

    if (tl < 2) {
        int t = nb * 2 + tl;

        float a21[21];
#pragma unroll
        for (int k = 0; k < 21; ++k) a21[k] = Cl[bl * 66 + tl * 32 + k];

        float L0 = a21[0] + b_clc[t * 2 + 0];
        float L1 = a21[1] + b_clc[t * 2 + 1];
        float mm = fmaxf(L0, L1);
        float e0 = __expf(L0 - mm), e1 = __expf(L1 - mm);
        float gate = e1 / (e0 + e1);

        float l1v[3];
        float m1 = -3.0e38f;
#pragma unroll
        for (int c = 0; c < 3; ++c) {
            l1v[c] = a21[2 + c] + b1[t * 3 + c];
            m1 = fmaxf(m1, l1v[c]);
        }
        float p1[3]; float S1 = 0.f;
#pragma unroll
        for (int c = 0; c < 3; ++c) { p1[c] = __expf(l1v[c] - m1); S1 += p1[c]; }
        float invS1g = gate / S1;

        float r0f = fmaxf(l1v[0], 0.f);
        float r1f = fmaxf(l1v[1], 0.f);
        float r2f = fmaxf(l1v[2], 0.f);

        const float* w2t = w2 + ((size_t)t * NW2ROW + NF) * 16;
        float l2[16]; float m2 = -3.0e38f;
#pragma unroll
        for (int nn = 0; nn < 16; ++nn) {
            float v = a21[5 + nn] + b2[t * 16 + nn];
            v = fmaf(r0f, w2t[nn], v);
            v = fmaf(r1f, w2t[16 + nn], v);
            v = fmaf(r2f, w2t[32 + nn], v);
            l2[nn] = v;
            m2 = fmaxf(m2, v);
        }
        float S2 = 0.f; float p2[16];
#pragma unroll
        for (int nn = 0; nn < 16; ++nn) { p2[nn] = __expf(l2[nn] - m2); S2 += p2[nn]; }
        float invS2g = gate * __frcp_rn(S2);

#pragma unroll
        for (int c = 0; c < 3; ++c) {
            int sl = cc[t * 3 + c];
            float pc = p1[c] * invS1g;
#pragma unroll
            for (int x = 0; x < 5; ++x) {
                if (sl == x) { s[x] += pc; s[5 + x] += gate; }
            }
        }
#pragma unroll
        for (int nn = 0; nn < 16; ++nn) s[10 + nn] += p2[nn] * invS2g;
        s[26] += gate;
    }

    if (tl == 1) {
#pragma unroll
        for (int k = 0; k < NP; ++k) red[k * 64 + bl] = s[k];
    }
    __syncthreads();
    if (tl != 0) return;

#pragma unroll
    for (int k = 0; k < NP; ++k) s[k] += red[k * 64 + bl];

    float* pt = ptl2 + (size_t)nb * NP * NB + m0 + bl;
#pragma unroll
    for (int k = 0; k < NP; ++k)
        pt[(size_t)k * NB] = s[k];
}

// ---------------------------------------------------------------------------
// Finalize (unchanged from R16): grid 16 x 1024; 4-phase LDS tree reduce.
// ---------------------------------------------------------------------------
__global__ __launch_bounds__(1024) void finalize_kernel(
    const float* __restrict__ ptl2, float* __restrict__ out)
{
    __shared__ float red[8][NP][64];
    int lane = threadIdx.x & 63;
    int w = threadIdx.x >> 6;
    int b = blockIdx.x * 64 + lane;

    float s[NP];
#pragma unroll
    for (int k = 0; k < NP; ++k) s[k] = 0.f;
#pragma unroll
    for (int i = 0; i < 2; ++i) {
        const float* pt = ptl2 + (size_t)(w * 2 + i) * NP * NB + b;
#pragma unroll
        for (int k = 0; k < NP; ++k) s[k] += pt[(size_t)k * NB];
    }

    if (w >= 8) {
#pragma unroll
        for (int k = 0; k < NP; ++k) red[w - 8][k][lane] = s[k];
    }
    __syncthreads();
    if (w < 8) {
#pragma unroll
        for (int k = 0; k < NP; ++k) s[k] += red[w][k][lane];
    }
    __syncthreads();
    if (w >= 4 && w < 8) {
#pragma unroll
        for (int k = 0; k < NP; ++k) red[w - 4][k][lane] = s[k];
    }
    __syncthreads();
    if (w < 4) {
#pragma unroll
        for (int k = 0; k < NP; ++k) s[k] += red[w][k][lane];
    }
    __syncthreads();
    if (w >= 2 && w < 4) {
#pragma unroll
        for (int k = 0; k < NP; ++k) red[w - 2][k][lane] = s[k];
    }
    __syncthreads();
    if (w < 2) {
#pragma unroll
        for (int k = 0; k < NP; ++k) s[k] += red[w][k][lane];
    }
    __syncthreads();
    if (w == 1) {
#pragma unroll
        for (int k = 0; k < NP; ++k) red[0][k][lane] = s[k];
    }
    __syncthreads();
    if (w != 0) return;
#pragma unroll
    for (int k = 0; k < NP; ++k) s[k] += red[0][k][lane];

    float* ob = out + (size_t)b * 21;
#pragma unroll
    for (int x = 0; x < 5; ++x) {
        float c = s[5 + x];
        ob[x] = (c > 0.f) ? (s[x] / c) : 0.f;
    }
    float invg = 1.f / s[26];
#pragma unroll
    for (int n = 0; n < 16; ++n) ob[5 + n] = s[10 + n] * invg;
}

// ---------------------------------------------------------------------------
extern "C" void kernel_launch(void* const* d_in, const int* in_sizes, int n_in,
                              void* d_out, int out_size, void* d_ws, size_t ws_size,
                              hipStream_t stream)
{
    const float* d     = (const float*)d_in[0];
    const int*   idx   = (const int*)  d_in[1];
    const int*   cc    = (const int*)  d_in[2];
    const float* w_clc = (const float*)d_in[3];
    const float* b_clc = (const float*)d_in[4];
    const float* w1    = (const float*)d_in[5];
    const float* b1    = (const float*)d_in[6];
    const float* w2    = (const float*)d_in[7];
    const float* b2    = (const float*)d_in[8];
    float* out = (float*)d_out;

    unsigned short* Wf = (unsigned short*)d_ws;            // [2048][2048] bf16
    unsigned short* db = Wf + (size_t)NN2 * ND;            // [1024][2048] bf16
    float* ptl2 = (float*)(db + (size_t)NB * ND);          // [32][27][1024] f32

    prep_kernel<<<640, 1024, 0, stream>>>(idx, w_clc, w1, w2, d, Wf, db);
    fused_kernel<<<dim3(32, 16), 256, 0, stream>>>(db, Wf, b_clc, b1, b2, w2, cc, ptl2);
    finalize_kernel<<<16, 1024, 0, stream>>>(ptl2, out);
}

// Round 18
// 40.257 us; speedup vs baseline: 1.0408x; 1.0408x over previous
//
#include <hip/hip_runtime.h>

// Problem constants
#define NT 64
#define NF 1024
#define NB 1024
#define ND 2048
#define NTP 32
#define NN2 (NT * NTP)
#define NP 27
#define NW2ROW 1027
#define BK 64
#define BM 64
#define BN 64

typedef __attribute__((ext_vector_type(8))) short short8;
typedef __attribute__((ext_vector_type(4))) float f32x4;

static __device__ __forceinline__ unsigned short f2bf(float x) {
    unsigned u = __float_as_uint(x);
    unsigned r = (u + 0x7FFFu + ((u >> 16) & 1u)) >> 16;   // RNE
    return (unsigned short)r;
}

// ---------------------------------------------------------------------------
// prep v6: grid 512 x 1024 (exactly 2 blocks/CU, one occupancy round — R16's
// 640-block grid had a 128-block straggler round). Block (t = bid>>3,
// je = bid&7) does its j-range scatter AND 1/512 of the d->bf16 convert
// (4 f32/thread, load issued early to overlap the masked gather latency).
// ---------------------------------------------------------------------------
__global__ __launch_bounds__(1024) void prep_kernel(
    const int* __restrict__ idx, const float* __restrict__ w_clc,
    const float* __restrict__ w1, const float* __restrict__ w2,
    const float* __restrict__ d, unsigned short* __restrict__ Wf,
    unsigned short* __restrict__ db)
{
    __shared__ __align__(16) float tile[21 * 256];   // 21,504 B
    int bid = blockIdx.x;
    int tid = threadIdx.x;

    // convert slice: load early (latency overlaps the scatter below)
    int i4 = (bid * 1024 + tid) * 4;
    float4 cv = *(const float4*)&d[i4];

    int t = bid >> 3, je = bid & 7;

    float4* tz = (float4*)tile;
    for (int i = tid; i < 1344; i += 1024) tz[i] = make_float4(0, 0, 0, 0);
    __syncthreads();

    {
        int f = tid;
        int j = idx[t * NF + f];
        if ((j >> 8) == je) {
            int jl = j & 255;
            float2 a = *(const float2*)&w_clc[(size_t)(t * NF + f) * 2];
            atomicAdd(&tile[0 * 256 + jl], a.x);
            atomicAdd(&tile[1 * 256 + jl], a.y);
            const float* p1 = &w1[(size_t)(t * NF + f) * 3];
            atomicAdd(&tile[2 * 256 + jl], p1[0]);
            atomicAdd(&tile[3 * 256 + jl], p1[1]);
            atomicAdd(&tile[4 * 256 + jl], p1[2]);
            const float* w2row = &w2[((size_t)t * NW2ROW + f) * 16];
            float4 q0 = *(const float4*)&w2row[0];
            float4 q1 = *(const float4*)&w2row[4];
            float4 q2 = *(const float4*)&w2row[8];
            float4 q3 = *(const float4*)&w2row[12];
            atomicAdd(&tile[ 5 * 256 + jl], q0.x);
            atomicAdd(&tile[ 6 * 256 + jl], q0.y);
            atomicAdd(&tile[ 7 * 256 + jl], q0.z);
            atomicAdd(&tile[ 8 * 256 + jl], q0.w);
            atomicAdd(&tile[ 9 * 256 + jl], q1.x);
            atomicAdd(&tile[10 * 256 + jl], q1.y);
            atomicAdd(&tile[11 * 256 + jl], q1.z);
            atomicAdd(&tile[12 * 256 + jl], q1.w);
            atomicAdd(&tile[13 * 256 + jl], q2.x);
            atomicAdd(&tile[14 * 256 + jl], q2.y);
            atomicAdd(&tile[15 * 256 + jl], q2.z);
            atomicAdd(&tile[16 * 256 + jl], q2.w);
            atomicAdd(&tile[17 * 256 + jl], q3.x);
            atomicAdd(&tile[18 * 256 + jl], q3.y);
            atomicAdd(&tile[19 * 256 + jl], q3.z);
            atomicAdd(&tile[20 * 256 + jl], q3.w);
        }
    }

    // store convert slice (independent of the tile; before the barrier)
    {
        union { unsigned short u[4]; uint2 v; } pk;
        pk.u[0] = f2bf(cv.x); pk.u[1] = f2bf(cv.y);
        pk.u[2] = f2bf(cv.z); pk.u[3] = f2bf(cv.w);
        *(uint2*)&db[i4] = pk.v;
    }
    __syncthreads();

    for (int i = tid; i < 672; i += 1024) {
        int c = i >> 5, off = (i & 31) * 8;
        const float* tr = &tile[c * 256 + off];
        union { unsigned short u[8]; uint4 v; } pk;
#pragma unroll
        for (int e = 0; e < 8; ++e) pk.u[e] = f2bf(tr[e]);
        *(uint4*)&Wf[(size_t)(t * NTP + c) * ND + je * 256 + off] = pk.v;
    }
    uint4 z = make_uint4(0, 0, 0, 0);
    for (int i = tid; i < 352; i += 1024) {
        int c = 21 + (i >> 5), off = (i & 31) * 8;
        *(uint4*)&Wf[(size_t)(t * NTP + c) * ND + je * 256 + off] = z;
    }
}

// ---------------------------------------------------------------------------
// Fused GEMM + epilogue — R16 geometry (64x64 tile, BK=64, 4 waves, 2x2
// frags), upgraded to a 3-BUFFER SINGLE-BARRIER pipeline. Depth-2 prefetch:
// STAGE@kt targets buf[(kt+2)%3]. The WAR barrier is provably redundant:
// barrier@kt happens-after every wave's MFMA@kt-1 (program order; MFMA's
// lgkm wait forces read completion), and buf[(kt+2)%3] == buf[(kt-1)%3] was
// last read at kt-1. vmcnt(4): tile kt's 4 loads done, tiles kt+1/kt+2 in
// flight (~2 kt-phases of hiding > ~500cyc load latency). 32 barriers total
// (was 64). LDS 48KB -> 2 blocks/CU.
// ---------------------------------------------------------------------------
__global__ __launch_bounds__(256, 2) void fused_kernel(
    const unsigned short* __restrict__ A,    // db [1024][2048]
    const unsigned short* __restrict__ Bm,   // Wf [2048][2048]
    const float* __restrict__ b_clc, const float* __restrict__ b1,
    const float* __restrict__ b2, const float* __restrict__ w2,
    const int* __restrict__ cc, float* __restrict__ ptl2)
{
    __shared__ __align__(16) char smem[49152];
    unsigned short (*As)[BM][BK] = (unsigned short(*)[BM][BK])smem;             // 3x8 KB
    unsigned short (*Bs)[BN][BK] = (unsigned short(*)[BN][BK])(smem + 24576);   // 3x8 KB
    float* Cl  = (float*)smem;              // [64][65] = 16,640 B (alias)
    float* red = (float*)(smem + 16896);    // [27][64] = 6,912 B

    int tid = threadIdx.x;
    int lane = tid & 63;
    int wv = tid >> 6;
    int wr = wv & 1;
    int wq = wv >> 1;
    int nb = blockIdx.x;
    int mb = blockIdx.y;
    int m0 = mb * BM;
    int n0 = nb * BN;
    int r0 = lane & 15;
    int kq = lane >> 4;
    int sx = r0 & 7;
    int sl0 = ((0 * 4 + kq) ^ sx) * 8;
    int sl1 = ((1 * 4 + kq) ^ sx) * 8;

    f32x4 acc[2][2];
#pragma unroll
    for (int mi = 0; mi < 2; ++mi)
#pragma unroll
        for (int ni = 0; ni < 2; ++ni) acc[mi][ni] = (f32x4)0.f;

#define STAGE(buf, kt)                                                          \
    {                                                                           \
        size_t koff = (size_t)(kt) * BK;                                        \
        _Pragma("unroll")                                                       \
        for (int p = 0; p < 2; ++p) {                                           \
            int chunk = p * 256 + tid;                                          \
            int row = chunk >> 3, c = chunk & 7;                                \
            int csw = (c ^ (row & 7)) * 8;                                      \
            const unsigned short* ga = A + (size_t)(m0 + row) * ND + koff + csw;\
            __builtin_amdgcn_global_load_lds(                                   \
                (const __attribute__((address_space(1))) void*)ga,              \
                (__attribute__((address_space(3))) void*)&As[buf][row][c * 8],  \
                16, 0, 0);                                                      \
        }                                                                       \
        _Pragma("unroll")                                                       \
        for (int p = 0; p < 2; ++p) {                                           \
            int chunk = p * 256 + tid;                                          \
            int row = chunk >> 3, c = chunk & 7;                                \
            int csw = (c ^ (row & 7)) * 8;                                      \
            const unsigned short* gb = Bm + (size_t)(n0 + row) * ND + koff + csw;\
            __builtin_amdgcn_global_load_lds(                                   \
                (const __attribute__((address_space(1))) void*)gb,              \
                (__attribute__((address_space(3))) void*)&Bs[buf][row][c * 8],  \
                16, 0, 0);                                                      \
        }                                                                       \
    }

    STAGE(0, 0);
    STAGE(1, 1);                 // 8 loads in flight

    for (int kt = 0; kt < 32; ++kt) {
        int cur = kt % 3;
        if (kt < 31)
            asm volatile("s_waitcnt vmcnt(4)" ::: "memory");   // tile kt done
        else
            asm volatile("s_waitcnt vmcnt(0)" ::: "memory");
        __builtin_amdgcn_s_barrier();          // all waves: tile kt ready AND
                                               // all reads of buf[(kt-1)%3] consumed
        __builtin_amdgcn_sched_barrier(0);

        short8 af[2][2], bf[2][2];
#pragma unroll
        for (int mi = 0; mi < 2; ++mi) {
            af[mi][0] = *(const short8*)&As[cur][wr*32 + mi*16 + r0][sl0];
            af[mi][1] = *(const short8*)&As[cur][wr*32 + mi*16 + r0][sl1];
        }
#pragma unroll
        for (int ni = 0; ni < 2; ++ni) {
            bf[ni][0] = *(const short8*)&Bs[cur][wq*32 + ni*16 + r0][sl0];
            bf[ni][1] = *(const short8*)&Bs[cur][wq*32 + ni*16 + r0][sl1];
        }
#pragma unroll
        for (int ks = 0; ks < 2; ++ks)
#pragma unroll
            for (int mi = 0; mi < 2; ++mi)
#pragma unroll
                for (int ni = 0; ni < 2; ++ni)
                    acc[mi][ni] = __builtin_amdgcn_mfma_f32_16x16x32_bf16(
                        af[mi][ks], bf[ni][ks], acc[mi][ni], 0, 0, 0);

        __builtin_amdgcn_sched_barrier(0);
        if (kt < 30) STAGE((kt + 2) % 3, kt + 2);
        __builtin_amdgcn_sched_barrier(0);
    }
#undef STAGE
    __builtin_amdgcn_s_barrier();   // reads of last buffer done before Cl alias

    // C -> LDS. b = wr*32+mi*16+kq*4+q, n = wq*32+ni*16+r0. Stride 65.
#pragma unroll
    for (int mi = 0; mi < 2; ++mi)
#pragma unroll
        for (int ni = 0; ni < 2; ++ni) {
            int n = wq * 32 + ni * 16 + r0;
            int bl = wr * 32 + mi * 16 + kq * 4;
#pragma unroll
            for (int q = 0; q < 4; ++q)
                Cl[(bl + q) * 65 + n] = acc[mi][ni][q];
        }
    __syncthreads();

    // ---- epilogue: waves 0-1 = trees 0-1 (wave-uniform t), lane = b ----
    int tl = tid >> 6;
    int bl = lane;
    float s[NP];
#pragma unroll
    for (int k = 0; k < NP; ++k) s[k] = 0.f;

    if (tl < 2) {
        int t = nb * 2 + tl;

        float a21[21];
#pragma unroll
        for (int k = 0; k < 21; ++k) a21[k] = Cl[bl * 65 + tl * 32 + k];

        float L0 = a21[0] + b_clc[t * 2 + 0];
        float L1 = a21[1] + b_clc[t * 2 + 1];
        float mm = fmaxf(L0, L1);
        float e0 = __expf(L0 - mm), e1 = __expf(L1 - mm);
        float gate = e1 / (e0 + e1);

        float l1v[3];
        float m1 = -3.0e38f;
#pragma unroll
        for (int c = 0; c < 3; ++c) {
            l1v[c] = a21[2 + c] + b1[t * 3 + c];
            m1 = fmaxf(m1, l1v[c]);
        }
        float p1[3]; float S1 = 0.f;
#pragma unroll
        for (int c = 0; c < 3; ++c) { p1[c] = __expf(l1v[c] - m1); S1 += p1[c]; }
        float invS1g = gate / S1;

        float r0f = fmaxf(l1v[0], 0.f);
        float r1f = fmaxf(l1v[1], 0.f);
        float r2f = fmaxf(l1v[2], 0.f);

        const float* w2t = w2 + ((size_t)t * NW2ROW + NF) * 16;
        float l2[16]; float m2 = -3.0e38f;
#pragma unroll
        for (int nn = 0; nn < 16; ++nn) {
            float v = a21[5 + nn] + b2[t * 16 + nn];
            v = fmaf(r0f, w2t[nn], v);
            v = fmaf(r1f, w2t[16 + nn], v);
            v = fmaf(r2f, w2t[32 + nn], v);
            l2[nn] = v;
            m2 = fmaxf(m2, v);
        }
        float S2 = 0.f; float p2[16];
#pragma unroll
        for (int nn = 0; nn < 16; ++nn) { p2[nn] = __expf(l2[nn] - m2); S2 += p2[nn]; }
        float invS2g = gate * __frcp_rn(S2);

#pragma unroll
        for (int c = 0; c < 3; ++c) {
            int sl = cc[t * 3 + c];
            float pc = p1[c] * invS1g;
#pragma unroll
            for (int x = 0; x < 5; ++x) {
                if (sl == x) { s[x] += pc; s[5 + x] += gate; }
            }
        }
#pragma unroll
        for (int nn = 0; nn < 16; ++nn) s[10 + nn] += p2[nn] * invS2g;
        s[26] += gate;
    }

    if (tl == 1) {
#pragma unroll
        for (int k = 0; k < NP; ++k) red[k * 64 + bl] = s[k];
    }
    __syncthreads();
    if (tl != 0) return;

#pragma unroll
    for (int k = 0; k < NP; ++k) s[k] += red[k * 64 + bl];

    float* pt = ptl2 + (size_t)nb * NP * NB + m0 + bl;
#pragma unroll
    for (int k = 0; k < NP; ++k)
        pt[(size_t)k * NB] = s[k];
}

// ---------------------------------------------------------------------------
// Finalize (unchanged): grid 16 x 1024; 4-phase LDS tree reduce.
// ---------------------------------------------------------------------------
__global__ __launch_bounds__(1024) void finalize_kernel(
    const float* __restrict__ ptl2, float* __restrict__ out)
{
    __shared__ float red[8][NP][64];
    int lane = threadIdx.x & 63;
    int w = threadIdx.x >> 6;
    int b = blockIdx.x * 64 + lane;

    float s[NP];
#pragma unroll
    for (int k = 0; k < NP; ++k) s[k] = 0.f;
#pragma unroll
    for (int i = 0; i < 2; ++i) {
        const float* pt = ptl2 + (size_t)(w * 2 + i) * NP * NB + b;
#pragma unroll
        for (int k = 0; k < NP; ++k) s[k] += pt[(size_t)k * NB];
    }

    if (w >= 8) {
#pragma unroll
        for (int k = 0; k < NP; ++k) red[w - 8][k][lane] = s[k];
    }
    __syncthreads();
    if (w < 8) {
#pragma unroll
        for (int k = 0; k < NP; ++k) s[k] += red[w][k][lane];
    }
    __syncthreads();
    if (w >= 4 && w < 8) {
#pragma unroll
        for (int k = 0; k < NP; ++k) red[w - 4][k][lane] = s[k];
    }
    __syncthreads();
    if (w < 4) {
#pragma unroll
        for (int k = 0; k < NP; ++k) s[k] += red[w][k][lane];
    }
    __syncthreads();
    if (w >= 2 && w < 4) {
#pragma unroll
        for (int k = 0; k < NP; ++k) red[w - 2][k][lane] = s[k];
    }
    __syncthreads();
    if (w < 2) {
#pragma unroll
        for (int k = 0; k < NP; ++k) s[k] += red[w][k][lane];
    }
    __syncthreads();
    if (w == 1) {
#pragma unroll
        for (int k = 0; k < NP; ++k) red[0][k][lane] = s[k];
    }
    __syncthreads();
    if (w != 0) return;
#pragma unroll
    for (int k = 0; k < NP; ++k) s[k] += red[0][k][lane];

    float* ob = out + (size_t)b * 21;
#pragma unroll
    for (int x = 0; x < 5; ++x) {
        float c = s[5 + x];
        ob[x] = (c > 0.f) ? (s[x] / c) : 0.f;
    }
    float invg = 1.f / s[26];
#pragma unroll
    for (int n = 0; n < 16; ++n) ob[5 + n] = s[10 + n] * invg;
}

// ---------------------------------------------------------------------------
extern "C" void kernel_launch(void* const* d_in, const int* in_sizes, int n_in,
                              void* d_out, int out_size, void* d_ws, size_t ws_size,
                              hipStream_t stream)
{
    const float* d     = (const float*)d_in[0];
    const int*   idx   = (const int*)  d_in[1];
    const int*   cc    = (const int*)  d_in[2];
    const float* w_clc = (const float*)d_in[3];
    const float* b_clc = (const float*)d_in[4];
    const float* w1    = (const float*)d_in[5];
    const float* b1    = (const float*)d_in[6];
    const float* w2    = (const float*)d_in[7];
    const float* b2    = (const float*)d_in[8];
    float* out = (float*)d_out;

    unsigned short* Wf = (unsigned short*)d_ws;            // [2048][2048] bf16
    unsigned short* db = Wf + (size_t)NN2 * ND;            // [1024][2048] bf16
    float* ptl2 = (float*)(db + (size_t)NB * ND);          // [32][27][1024] f32

    prep_kernel<<<512, 1024, 0, stream>>>(idx, w_clc, w1, w2, d, Wf, db);
    fused_kernel<<<dim3(32, 16), 256, 0, stream>>>(db, Wf, b_clc, b1, b2, w2, cc, ptl2);
    finalize_kernel<<<16, 1024, 0, stream>>>(ptl2, out);
}